// Round 1
// 175.696 us; speedup vs baseline: 1.0014x; 1.0014x over previous
//
#include <hip/hip_runtime.h>
#include <math.h>

#define N_VOX 32768
#define N_EMB 8192
#define DIM 64
#define NCHUNK 8
#define CODES_PER_CHUNK (N_EMB / NCHUNK)       // 1024
#define TILES_PER_CHUNK (CODES_PER_CHUNK / 32) // 32
#define NTILES (N_EMB / 32)                    // 256
#define TILE_BYTES 8192                        // bh[4x1KB] | bl[4x1KB]
#define CHUNK_BYTES (TILES_PER_CHUNK * TILE_BYTES)

typedef _Float16 half8 __attribute__((ext_vector_type(8)));
typedef float floatx16 __attribute__((ext_vector_type(16)));

#define FP16_MIN_NORMAL 6.1035156e-5f
#define LO_SCALE 2048.0f

// -------- kernel A: fused esq + B-fragment stream build (validated R9-R12) ---
// Same stream/c0 layout as before; now 256 thr/tile (thread = one (o,lane)
// slice, 4x parallelism vs the 64-thr version that ran 1 wave/CU).
// 32x32x16 f16 B-frag per K-chunk o: lane l holds code n=l&31, k=o*16+(l>>5)*8+j.
// Tile (32 codes): [bh o=0..3 | bl o=0..3]; c0arr[code] = -1024*esq.
__global__ __launch_bounds__(256) void cbprep_kernel(const float* __restrict__ cb,
                                                     char* __restrict__ stream,
                                                     float* __restrict__ c0arr) {
    __shared__ float red[256];
    int tid  = threadIdx.x;                      // 0..255
    int l    = tid & 63;
    int o    = tid >> 6;                         // K-chunk 0..3
    int m    = l & 31;
    int kg   = l >> 5;
    int tile = blockIdx.x;                       // 0..255
    char* tbase = stream + (size_t)tile * TILE_BYTES;
    int code = tile * 32 + m;

    const float* p = cb + (size_t)code * DIM + o * 16 + kg * 8;
    float ss = 0.f;
    half8 h, lo;
    #pragma unroll
    for (int j = 0; j < 8; ++j) {
        float x = p[j];
        ss = fmaf(x, x, ss);
        _Float16 hi = (_Float16)x;
        float hf = (float)hi;
        if (fabsf(hf) < FP16_MIN_NORMAL) { hi = (_Float16)0.f; hf = 0.f; }
        h[j]  = hi;
        lo[j] = (_Float16)((x - hf) * LO_SCALE);
    }
    *(half8*)(tbase +        o * 1024 + l * 16) = h;
    *(half8*)(tbase + 4096 + o * 1024 + l * 16) = lo;

    red[tid] = ss;
    __syncthreads();
    if (tid < 32) {                              // tid == m here
        float s = 0.f;
        #pragma unroll
        for (int q = 0; q < 8; ++q) s += red[tid + q * 32];
        c0arr[tile * 32 + tid] = -1024.0f * s;
    }
}

// -------- kernel B: MFMA argmin scan — now 3-deep counted-vmcnt pipeline -----
// Block = 8 waves (512 thr), same chunk. Wave owns 32 rows x one chunk
// (1024 codes, 32 tiles). Per tile: 8KB staged global->LDS (1KB per wave,
// global_load_lds width 16). NEW (T3+T4): 4 LDS buffers, stage 3 tiles
// ahead, per-tile sync = s_waitcnt vmcnt(2) + raw s_barrier (never drain
// vmcnt in the loop). c0 moved to LDS so the STAGE is the ONLY in-loop
// vmem op and vmcnt counting is exact. Safety: at iter-t barrier every
// wave's stage-t retired (in-order vmcnt) and every wave's tile-(t-1)
// ds_reads retired (lgkmcnt before its MFMAs), so STAGE(t+3) into
// buf[(t-1)&3] after the barrier is race-free.
// acc = 2048*(dot - esq/2), A-side scale (zhs=2048*zh exact).
// Maximize, tie -> earlier tile/lower id. Math + mapping = validated R8-R12.
__global__ __launch_bounds__(512) void scan_kernel(const float* __restrict__ z,
                                                   const char* __restrict__ stream,
                                                   const float* __restrict__ c0arr,
                                                   float* __restrict__ cand_val,
                                                   int* __restrict__ cand_idx) {
    __shared__ __align__(16) char lds[4 * TILE_BYTES + CODES_PER_CHUNK * 4];
    float* c0_lds = (float*)(lds + 4 * TILE_BYTES);
    int tid   = threadIdx.x;
    int l     = tid & 63;
    int w     = tid >> 6;                        // wave 0..7
    int chunk = blockIdx.x & (NCHUNK - 1);
    int rg    = blockIdx.x >> 3;                 // 0..127, 256 rows per block
    int m     = l & 31;                          // A row in tile / B col (code)
    int kg    = l >> 5;
    int rowBase = rg * 256 + w * 32;             // wave's 32 rows

    // A fragments: zh (unscaled), zl = 2048*res, zhs = 2048*zh (exact shift)
    half8 zh[4], zl[4], zhs[4];
    const float* zrow = z + (size_t)(rowBase + m) * DIM + kg * 8;
    #pragma unroll
    for (int o = 0; o < 4; ++o) {
        const float* p = zrow + o * 16;
        #pragma unroll
        for (int j = 0; j < 8; ++j) {
            float x = p[j];
            _Float16 hi = (_Float16)x;
            float hf = (float)hi;
            if (fabsf(hf) < FP16_MIN_NORMAL) { hi = (_Float16)0.f; hf = 0.f; }
            zh[o][j] = hi;
            zl[o][j] = (_Float16)((x - hf) * LO_SCALE);
        }
        zhs[o] = zh[o] * (_Float16)2048.0f;
    }

    const char*  sbase = stream + (size_t)chunk * CHUNK_BYTES;
    const float* c0p   = c0arr + chunk * CODES_PER_CHUNK;

    float best[16];
    int   bt[16];
    #pragma unroll
    for (int i = 0; i < 16; ++i) { best[i] = -3.4e38f; bt[i] = 0; }

    // stage one 8KB tile: wave w issues seg w (1KB, lane l -> +l*16)
#define STAGE(gt, lb)                                                              \
    do {                                                                           \
        const char* _g = (gt) + w * 1024 + l * 16;                                 \
        char*       _d = (lb) + w * 1024 + l * 16;                                 \
        __builtin_amdgcn_global_load_lds(                                          \
            (const __attribute__((address_space(1))) void*)_g,                     \
            (__attribute__((address_space(3))) void*)_d, 16, 0, 0);                \
    } while (0)

    // prologue: stage tiles 0..2 into bufs 0..2, fill c0 LDS, full drain once
    STAGE(sbase,                        lds);
    STAGE(sbase + (size_t)TILE_BYTES,   lds + TILE_BYTES);
    STAGE(sbase + 2 * (size_t)TILE_BYTES, lds + 2 * TILE_BYTES);
    c0_lds[tid]       = c0p[tid];
    c0_lds[tid + 512] = c0p[tid + 512];
    __syncthreads();                             // drains vmcnt to 0 (once)

    for (int t = 0; t < TILES_PER_CHUNK; ++t) {
        // own stage-t retired: keep newest {t+1,t+2} in flight (tail: fewer)
        if (t < TILES_PER_CHUNK - 2)
            asm volatile("s_waitcnt vmcnt(2)" ::: "memory");
        else if (t == TILES_PER_CHUNK - 2)
            asm volatile("s_waitcnt vmcnt(1)" ::: "memory");
        else
            asm volatile("s_waitcnt vmcnt(0)" ::: "memory");
        __builtin_amdgcn_s_barrier();            // all waves: stage t landed
        asm volatile("" ::: "memory");           // pin ds_reads below barrier

        if (t + 3 < TILES_PER_CHUNK)             // overwrites buf[(t-1)&3]
            STAGE(sbase + (size_t)(t + 3) * TILE_BYTES,
                  lds + ((t + 3) & 3) * TILE_BYTES);

        const char* lb = lds + (t & 3) * TILE_BYTES;
        float c0 = c0_lds[t * 32 + m];           // tile t's -1024*esq
        half8 bh[4], bl[4];
        #pragma unroll
        for (int o = 0; o < 4; ++o) {
            bh[o] = *(const half8*)(lb +        o * 1024 + l * 16);
            bl[o] = *(const half8*)(lb + 4096 + o * 1024 + l * 16);
        }

        floatx16 acc;
        #pragma unroll
        for (int i = 0; i < 16; ++i) acc[i] = c0;
        #pragma unroll
        for (int o = 0; o < 4; ++o) {
            acc = __builtin_amdgcn_mfma_f32_32x32x16_f16(zhs[o], bh[o], acc, 0, 0, 0);
            acc = __builtin_amdgcn_mfma_f32_32x32x16_f16(zl[o],  bh[o], acc, 0, 0, 0);
            acc = __builtin_amdgcn_mfma_f32_32x32x16_f16(zh[o],  bl[o], acc, 0, 0, 0);
        }
        #pragma unroll
        for (int i = 0; i < 16; ++i)
            if (acc[i] > best[i]) { best[i] = acc[i]; bt[i] = t; }
    }
#undef STAGE

    // Cross-lane argmax over the 32 cols (lane bits 0..4); tie -> lower index.
    // kg=0/1 halves hold different rows; both write their own rows (R8 mapping).
    #pragma unroll
    for (int i = 0; i < 16; ++i) {
        float v  = best[i];
        int   id = bt[i] * 32 + m;               // code index within chunk
        #pragma unroll
        for (int off = 1; off < 32; off <<= 1) {
            float ov = __shfl_xor(v, off, 64);
            int   oi = __shfl_xor(id, off, 64);
            if (ov > v || (ov == v && oi < id)) { v = ov; id = oi; }
        }
        if (m == 0) {
            int row = rowBase + (i & 3) + 8 * (i >> 2) + 4 * kg;
            cand_val[chunk * N_VOX + row] = v;   // winning scaled score
            cand_idx[chunk * N_VOX + row] = chunk * CODES_PER_CHUNK + id;
        }
    }
}

// -------- kernel C: pick max stored score + gather (no re-score) -------------
// 8 lanes per row: lane c reads chunk c's (val, idx); width-8 shuffle argmax
// (tie -> lower id) — identical ordering semantics to scan's within-chunk
// reduce, so cross-chunk pick is consistent with the validated pipeline.
__global__ __launch_bounds__(256) void finalize_kernel(const float* __restrict__ z,
                                                       const float* __restrict__ cb,
                                                       const float* __restrict__ cand_val,
                                                       const int* __restrict__ cand_idx,
                                                       float* __restrict__ out,
                                                       float* __restrict__ partials) {
    int g    = blockIdx.x * 256 + threadIdx.x;
    int row  = g >> 3;
    int c    = g & 7;                  // chunk / candidate 0..7

    float v  = cand_val[c * N_VOX + row];
    int   id = cand_idx[c * N_VOX + row];
    #pragma unroll
    for (int off = 1; off < 8; off <<= 1) {
        float ov = __shfl_xor(v, off, 8);
        int   oi = __shfl_xor(id, off, 8);
        if (ov > v || (ov == v && oi < id)) { v = ov; id = oi; }
    }
    // all 8 lanes hold the winning id for this row

    if (c == 0)
        out[(size_t)N_VOX * DIM + 2 + row] = (float)id;

    // cooperative gather+write: lane handles elements [c*8, c*8+8)
    const float4* zp = (const float4*)(z  + (size_t)row * DIM + c * 8);
    const float4* qp = (const float4*)(cb + (size_t)id  * DIM + c * 8);
    float4*       op = (float4*)(out + (size_t)row * DIM + c * 8);
    float ss = 0.f;
    #pragma unroll
    for (int d = 0; d < 2; ++d) {
        float4 zt = zp[d], qt = qp[d];
        float dx = qt.x - zt.x, dy = qt.y - zt.y;
        float dz = qt.z - zt.z, dw = qt.w - zt.w;
        float4 o;
        o.x = zt.x + dx; o.y = zt.y + dy;   // mirrors reference z + (q - z)
        o.z = zt.z + dz; o.w = zt.w + dw;
        op[d] = o;
        ss += dx*dx + dy*dy + dz*dz + dw*dw;
    }

    __shared__ float red[256];
    red[threadIdx.x] = ss;
    __syncthreads();
    #pragma unroll
    for (int s = 128; s > 0; s >>= 1) {
        if (threadIdx.x < s) red[threadIdx.x] += red[threadIdx.x + s];
        __syncthreads();
    }
    if (threadIdx.x == 0) partials[blockIdx.x] = red[0];
}

// -------- kernel D: reduce 1024 partials -> both losses --------
__global__ __launch_bounds__(256) void loss_kernel(const float* __restrict__ partials,
                                                   float* __restrict__ out) {
    __shared__ float red[256];
    red[threadIdx.x] = (partials[threadIdx.x]       + partials[threadIdx.x + 256])
                     + (partials[threadIdx.x + 512] + partials[threadIdx.x + 768]);
    __syncthreads();
    #pragma unroll
    for (int st = 128; st > 0; st >>= 1) {
        if (threadIdx.x < st) red[threadIdx.x] += red[threadIdx.x + st];
        __syncthreads();
    }
    if (threadIdx.x == 0) {
        float mean = red[0] / (float)((size_t)N_VOX * DIM);
        out[(size_t)N_VOX * DIM + 0] = mean;
        out[(size_t)N_VOX * DIM + 1] = mean;
    }
}

extern "C" void kernel_launch(void* const* d_in, const int* in_sizes, int n_in,
                              void* d_out, int out_size, void* d_ws, size_t ws_size,
                              hipStream_t stream) {
    const float* z  = (const float*)d_in[0];   // [32768, 64]
    const float* cb = (const float*)d_in[1];   // [8192, 64]
    float* out = (float*)d_out;

    // ws: stream [2 MB] | c0arr [32 KB] | cand_val [1 MB] | cand_idx [1 MB] | partials [4 KB]
    char*  bstream  = (char*)d_ws;
    float* c0arr    = (float*)(bstream + (size_t)NTILES * TILE_BYTES);
    float* cand_val = c0arr + N_EMB;
    int*   cand_idx = (int*)(cand_val + (size_t)NCHUNK * N_VOX);
    float* partials = (float*)(cand_idx + (size_t)NCHUNK * N_VOX);

    cbprep_kernel  <<<dim3(NTILES), dim3(256), 0, stream>>>(cb, bstream, c0arr);
    scan_kernel    <<<dim3((N_VOX / 256) * NCHUNK), dim3(512), 0, stream>>>(z, bstream, c0arr, cand_val, cand_idx);
    finalize_kernel<<<dim3(N_VOX * 8 / 256), dim3(256), 0, stream>>>(z, cb, cand_val, cand_idx, out, partials);
    loss_kernel    <<<1, 256, 0, stream>>>(partials, out);
}